// Round 1
// baseline (50.556 us; speedup 1.0000x reference)
//
#include <hip/hip_runtime.h>

// Wiener-Hammerstein: y1 = IIR1(u) [n_k=1]; v = whf(y1); out = IIR2(v) [n_k=0]
// Overlap-save chunked recurrence: per-thread 64-sample chunk with warm-up
// (W1=64 for filter1, pole modulus ~0.746 -> err ~1e-8;
//  W2=192 for filter2, pole modulus ~0.899 -> err ~1.4e-9; thr = 2.4e-2).

constexpr int T_LEN = 16384;
constexpr int CHUNK = 64;   // outputs per thread
constexpr int NTH   = 256;  // threads per block = chunks per row
constexpr int W1    = 64;   // stage-1 warm-up
constexpr int W2    = 192;  // stage-2 warm-up

__global__ __launch_bounds__(NTH, 2)
void whsys_kernel(const float* __restrict__ u,
                  const float* __restrict__ b1, const float* __restrict__ a1,
                  const float* __restrict__ b2, const float* __restrict__ a2,
                  float* __restrict__ out)
{
    // time-transposed layout: [t % 64][chunk] -> lanes at fixed row, consecutive
    // cols -> conflict-free LDS for both the stage-1 writes and stage-2 reads.
    __shared__ float v_lds[CHUNK][NTH];   // 64 KB

    const int row = blockIdx.x;
    const int c   = threadIdx.x;
    const float* __restrict__ urow = u   + (size_t)row * T_LEN;
    float*       __restrict__ orow = out + (size_t)row * T_LEN;

    const float b10 = b1[0], b11 = b1[1], b12 = b1[2];
    const float a10 = a1[0], a11 = a1[1], a12 = a1[2];
    const float b20 = b2[0], b21 = b2[1], b22 = b2[2];
    const float a20 = a2[0], a21 = a2[1], a22 = a2[2];

    // ---------------- stage 1: y1 = IIR(b1,a1,n_k=1)(u); v = whf(y1) --------
    {
        const int base = c * CHUNK - W1;          // first (warm-up) time index
        float u1 = 0.f, u2 = 0.f, u3 = 0.f;       // u[tau-1], u[tau-2], u[tau-3]
        float y1 = 0.f, y2 = 0.f, y3 = 0.f;       // y[tau-1..tau-3]
        #pragma unroll
        for (int q = 0; q < (W1 + CHUNK) / 4; ++q) {
            const int tau = base + q * 4;          // multiple of 4, quad-aligned
            const int ta  = tau < 0 ? 0 : tau;     // safe address, masked below
            float4 uq = *reinterpret_cast<const float4*>(urow + ta);
            if (tau < 0) uq = make_float4(0.f, 0.f, 0.f, 0.f);
            float uv[4] = {uq.x, uq.y, uq.z, uq.w};
            #pragma unroll
            for (int e = 0; e < 4; ++e) {
                const int s = q * 4 + e;
                const float x = b10 * u1 + b11 * u2 + b12 * u3;   // n_k=1 FIR
                const float y = x - a10 * y1 - a11 * y2 - a12 * y3;
                u3 = u2; u2 = u1; u1 = uv[e];
                y3 = y2; y2 = y1; y1 = y;
                if (s >= W1) {
                    // whf(y) = -elu(-(10/11) y)
                    const float z = -0.9090909090909091f * y;
                    const float w = (z > 0.f) ? -z : (1.0f - __expf(z));
                    v_lds[s - W1][c] = w;
                }
            }
        }
    }
    __syncthreads();
    // ---------------- stage 2: out = IIR(b2,a2,n_k=0)(v) --------------------
    {
        const int base = c * CHUNK - W2;
        float v1 = 0.f, v2 = 0.f;                 // v[tau-1], v[tau-2]
        float w1 = 0.f, w2 = 0.f, w3 = 0.f;       // y[tau-1..tau-3]
        float oq[4];
        #pragma unroll
        for (int s = 0; s < W2 + CHUNK; ++s) {
            const int tau = base + s;
            const int ta  = tau < 0 ? 0 : tau;
            float vt = v_lds[ta & (CHUNK - 1)][ta >> 6];  // row/col fold to imm
            if (tau < 0) vt = 0.f;
            const float x = b20 * vt + b21 * v1 + b22 * v2;  // n_k=0 FIR
            const float y = x - a20 * w1 - a21 * w2 - a22 * w3;
            v2 = v1; v1 = vt;
            w3 = w2; w2 = w1; w1 = y;
            if (s >= W2) {
                const int o = s - W2;
                oq[o & 3] = y;
                if ((o & 3) == 3)
                    *reinterpret_cast<float4*>(orow + base + s - 3) =
                        make_float4(oq[0], oq[1], oq[2], oq[3]);
            }
        }
    }
}

extern "C" void kernel_launch(void* const* d_in, const int* in_sizes, int n_in,
                              void* d_out, int out_size, void* d_ws, size_t ws_size,
                              hipStream_t stream) {
    const float* u  = (const float*)d_in[0];
    const float* b1 = (const float*)d_in[1];
    const float* a1 = (const float*)d_in[2];
    const float* b2 = (const float*)d_in[3];
    const float* a2 = (const float*)d_in[4];
    float* out = (float*)d_out;

    const int B = in_sizes[0] / T_LEN;   // 512
    whsys_kernel<<<B, NTH, 0, stream>>>(u, b1, a1, b2, a2, out);
}

// Round 2
// 35.805 us; speedup vs baseline: 1.4120x; 1.4120x over previous
//
#include <hip/hip_runtime.h>

// Wiener-Hammerstein, fused single-pass:
//   y1 = IIR(b1,a1,n_k=1)(u);  v = whf(y1);  out = IIR(b2,a2,n_k=0)(v)
// Overlap-save: thread owns a 64-sample chunk, runs the fused recurrence from
// zero state starting WARM=144 samples early (W1=48 stage-1-only prologue,
// pole modulus 0.75 -> 1e-6; W2=96 joint warm-up, pole modulus 0.90 -> 4e-5).
// Outputs staged through swizzled LDS for fully-coalesced float4 stores
// (R1 showed 4.6x HBM write amplification from 256B-strided lane stores).

constexpr int T_LEN = 16384;
constexpr int CHUNK = 64;    // outputs per thread
constexpr int NTH   = 256;   // threads per block = chunks per row
constexpr int W1    = 48;    // stage-1-only prologue iters
constexpr int W2    = 96;    // joint warm-up iters
constexpr int WARM  = W1 + W2;        // 144
constexpr int ITERS = WARM + CHUNK;   // 208

__global__ __launch_bounds__(NTH, 2)
void whsys_kernel(const float* __restrict__ u,
                  const float* __restrict__ b1v, const float* __restrict__ a1v,
                  const float* __restrict__ b2v, const float* __restrict__ a2v,
                  float* __restrict__ out)
{
    // o_lds[j][c ^ (j & ~3)]: XOR col-swizzle keeps BOTH the per-iteration
    // writes (lanes vary c, fixed j) and the transposed reads (rows 4l..4l+3,
    // col (i*16+h)^4l) at exactly 2 lanes/bank (free on CDNA4).
    __shared__ float o_lds[CHUNK][NTH];   // 64 KB

    const int row = blockIdx.x;
    const int c   = threadIdx.x;
    const float* __restrict__ urow = u   + (size_t)row * T_LEN;
    float*       __restrict__ orow = out + (size_t)row * T_LEN;

    const float b10=b1v[0], b11=b1v[1], b12=b1v[2];
    const float a10=a1v[0], a11=a1v[1], a12=a1v[2];
    const float b20=b2v[0], b21=b2v[1], b22=b2v[2];
    const float a20=a2v[0], a21=a2v[1], a22=a2v[2];

    const int base = c * CHUNK - WARM;    // multiple of 4 (quad-aligned)

    // recurrence state (register-renamed by full unroll of the 4-step body)
    float u1=0.f,u2=0.f,u3=0.f, y1=0.f,y2=0.f,y3=0.f;   // stage 1
    float v1=0.f,v2=0.f, w1=0.f,w2=0.f,w3=0.f;          // stage 2

    auto step1 = [&](float ut) -> float {
        const float x = fmaf(b12,u3, fmaf(b11,u2, b10*u1));   // n_k=1 FIR
        const float y = fmaf(-a10,y1, fmaf(-a11,y2, fmaf(-a12,y3, x)));
        u3=u2; u2=u1; u1=ut;
        y3=y2; y2=y1; y1=y;
        return y;
    };
    auto nl = [&](float y) -> float {                          // -elu(-10/11 y)
        const float e = 1.f - __expf(-0.9090909090909091f * y);
        return (y < 0.f) ? 0.9090909090909091f * y : e;
    };
    auto step2 = [&](float vt) -> float {
        const float x = fmaf(b22,v2, fmaf(b21,v1, b20*vt));    // n_k=0 FIR
        const float w = fmaf(-a20,w1, fmaf(-a21,w2, fmaf(-a22,w3, x)));
        v2=v1; v1=vt;
        w3=w2; w2=w1; w1=w;
        return w;
    };

    int s = 0;
    // ---- phase 1: stage-1 only (stage-2 zero-init absorbed by W2) ----------
    #pragma unroll
    for (int q = 0; q < W1/4; ++q, s += 4) {
        const int tau = base + s;
        const float4 ur = *reinterpret_cast<const float4*>(urow + (tau < 0 ? 0 : tau));
        const float4 uq = (tau >= 0) ? ur : make_float4(0.f,0.f,0.f,0.f);
        step1(uq.x); step1(uq.y); step1(uq.z); step1(uq.w);
    }
    // ---- phase 2: full pipeline, discard ------------------------------------
    #pragma unroll 4
    for (int q = 0; q < W2/4; ++q, s += 4) {
        const int tau = base + s;
        const float4 ur = *reinterpret_cast<const float4*>(urow + (tau < 0 ? 0 : tau));
        const float4 uq = (tau >= 0) ? ur : make_float4(0.f,0.f,0.f,0.f);
        step2(nl(step1(uq.x)));
        step2(nl(step1(uq.y)));
        step2(nl(step1(uq.z)));
        step2(nl(step1(uq.w)));
    }
    // ---- phase 3: full pipeline, keep -> swizzled LDS -----------------------
    #pragma unroll 4
    for (int q = 0; q < CHUNK/4; ++q, s += 4) {
        const int tau = base + s;                 // >= 0 for all threads here
        const float4 uq = *reinterpret_cast<const float4*>(urow + tau);
        const int j = s - WARM;                   // multiple of 4
        o_lds[j+0][c ^ j] = step2(nl(step1(uq.x)));   // (j+e)&~3 == j
        o_lds[j+1][c ^ j] = step2(nl(step1(uq.y)));
        o_lds[j+2][c ^ j] = step2(nl(step1(uq.z)));
        o_lds[j+3][c ^ j] = step2(nl(step1(uq.w)));
    }
    __syncthreads();

    // ---- coalesced store: thread c covers t = i*1024 + c*4 .. +3 ------------
    const int l = c & 15, h = c >> 4;
    const int jb = l * 4;                         // row group (j = jb + e)
    #pragma unroll
    for (int i = 0; i < T_LEN / (NTH * 4); ++i) { // 16
        const int col = (i * 16 + h) ^ jb;        // undo write swizzle
        float4 o;
        o.x = o_lds[jb + 0][col];
        o.y = o_lds[jb + 1][col];
        o.z = o_lds[jb + 2][col];
        o.w = o_lds[jb + 3][col];
        *reinterpret_cast<float4*>(orow + i * 1024 + c * 4) = o;
    }
}

extern "C" void kernel_launch(void* const* d_in, const int* in_sizes, int n_in,
                              void* d_out, int out_size, void* d_ws, size_t ws_size,
                              hipStream_t stream) {
    const float* u  = (const float*)d_in[0];
    const float* b1 = (const float*)d_in[1];
    const float* a1 = (const float*)d_in[2];
    const float* b2 = (const float*)d_in[3];
    const float* a2 = (const float*)d_in[4];
    float* out = (float*)d_out;

    const int B = in_sizes[0] / T_LEN;   // 512
    whsys_kernel<<<B, NTH, 0, stream>>>(u, b1, a1, b2, a2, out);
}

// Round 3
// 27.278 us; speedup vs baseline: 1.8533x; 1.3126x over previous
//
#include <hip/hip_runtime.h>

// Wiener-Hammerstein fused overlap-save, LDS-resident u.
//   y1 = IIR(b1,a1,n_k=1)(u);  v = whf(y1);  out = IIR(b2,a2,n_k=0)(v)
// Thread owns a 64-sample chunk; recurrence started WARM=112 samples early
// from zero state (W1=32 stage-1-only, pole^32 ~ 8e-5; W2=80 fused, pole^80
// ~ 2e-4; threshold 2.4e-2). R2 showed 817 GB/s / 10% HBM: cost was 4x L2
// read amplification from 256B-strided lane loads -> stage u in LDS with a
// transposed XOR-swizzled layout (conflict-free both directions), coalesced
// float4 global loads, and keep the coalesced LDS-staged stores from R2.

constexpr int T_LEN  = 16384;
constexpr int CHUNK  = 64;    // outputs per thread
constexpr int NTH    = 256;   // threads per block = chunks per row
constexpr int W1     = 32;    // stage-1-only prologue
constexpr int W2     = 80;    // fused warm-up
constexpr int WARM   = W1 + W2;       // 112
constexpr int OROWS  = 16;    // output staging rows per pass
constexpr int PASSES = CHUNK / OROWS; // 4

__global__ __launch_bounds__(NTH, 2)
void whsys_kernel(const float* __restrict__ u,
                  const float* __restrict__ b1v, const float* __restrict__ a1v,
                  const float* __restrict__ b2v, const float* __restrict__ a2v,
                  float* __restrict__ out)
{
    // u_T[r][k ^ (r&31)] = u[k*64 + r]: transposed so compute reads (fixed r,
    // consecutive k across lanes) are conflict-free; XOR swizzle makes the
    // phase-0 transposed writes conflict-free too (verified: 2 lanes/bank).
    __shared__ float u_T[64 * 256];       // 64 KB
    __shared__ float o_lds[OROWS][NTH];   // 16 KB  (total 80 KB -> 2 blk/CU)

    const int row = blockIdx.x;
    const int c   = threadIdx.x;
    const float* __restrict__ urow = u   + (size_t)row * T_LEN;
    float*       __restrict__ orow = out + (size_t)row * T_LEN;

    const float b10=b1v[0], b11=b1v[1], b12=b1v[2];
    const float a10=a1v[0], a11=a1v[1], a12=a1v[2];
    const float b20=b2v[0], b21=b2v[1], b22=b2v[2];
    const float a20=a2v[0], a21=a2v[1], a22=a2v[2];

    // ---- phase 0: coalesced global float4 -> transposed swizzled LDS ------
    #pragma unroll
    for (int q = 0; q < T_LEN / (NTH * 4); ++q) {   // 16
        const int t0 = q * 1024 + c * 4;
        const float4 v = *reinterpret_cast<const float4*>(urow + t0);
        const float vv[4] = {v.x, v.y, v.z, v.w};
        #pragma unroll
        for (int e = 0; e < 4; ++e) {
            const int t = t0 + e;
            const int r = t & 63, k = t >> 6;
            u_T[r * 256 + (k ^ (r & 31))] = vv[e];
        }
    }
    __syncthreads();

    // ---- recurrence state (register-renamed by full unroll) ----------------
    float u1=0.f,u2=0.f,u3=0.f, y1=0.f,y2=0.f,y3=0.f;   // stage 1
    float v1=0.f,v2=0.f, w1=0.f,w2=0.f,w3=0.f;          // stage 2

    auto step1 = [&](float ut) -> float {
        const float x = fmaf(b12,u3, fmaf(b11,u2, b10*u1));   // n_k=1 FIR
        const float y = fmaf(-a10,y1, fmaf(-a11,y2, fmaf(-a12,y3, x)));
        u3=u2; u2=u1; u1=ut;
        y3=y2; y2=y1; y1=y;
        return y;
    };
    auto nl = [&](float y) -> float {                    // -elu(-10/11 y)
        const float e = 1.f - __expf(-0.9090909090909091f * y);
        return (y < 0.f) ? 0.9090909090909091f * y : e;
    };
    auto step2 = [&](float vt) -> float {
        const float x = fmaf(b22,v2, fmaf(b21,v1, b20*vt));   // n_k=0 FIR
        const float w = fmaf(-a20,w1, fmaf(-a21,w2, fmaf(-a22,w3, x)));
        v2=v1; v1=vt;
        w3=w2; w2=w1; w1=w;
        return w;
    };

    // t = 64c + s - WARM = 64*kseg + r; kseg: [c-2 (s<48), c-1 (48<=s<112), c]
    // r is compile-time under full unroll -> ds_read offset immediate.
    const int k0 = c - 2, k1 = c - 1;
    const int k0c = (k0 < 0) ? 0 : k0;   // clamp; value zeroed by mask
    const int k1c = (k1 < 0) ? 0 : k1;
    const float m0 = (k0 < 0) ? 0.f : 1.f;
    const float m1 = (k1 < 0) ? 0.f : 1.f;

    auto rd = [&](int kq, int r_) -> float {             // r_ compile-time
        return u_T[r_ * 256 + (kq ^ (r_ & 31))];
    };

    // ---- phase 1: stage-1 only, s = 0..31  (r = s+16, k = c-2) -------------
    #pragma unroll
    for (int s = 0; s < W1; ++s)
        step1(rd(k0c, s + 16) * m0);

    // ---- phase 2a: fused discard, s = 32..47 (r = s+16, k = c-2) -----------
    #pragma unroll
    for (int s = W1; s < 48; ++s)
        step2(nl(step1(rd(k0c, s + 16) * m0)));

    // ---- phase 2b: fused discard, s = 48..111 (r = s-48, k = c-1) ----------
    #pragma unroll
    for (int s = 48; s < WARM; ++s)
        step2(nl(step1(rd(k1c, s - 48) * m1)));

    // ---- phase 3: fused keep, j = 0..63 (r = j, k = c), staged stores ------
    #pragma unroll
    for (int p = 0; p < PASSES; ++p) {
        #pragma unroll
        for (int jj = 0; jj < OROWS; ++jj) {
            const int j = p * OROWS + jj;
            o_lds[jj][c] = step2(nl(step1(rd(c, j))));
        }
        __syncthreads();
        // coalesced store: quarter-wave covers one full 64B line
        const int jj4 = 4 * (c & 3);
        #pragma unroll
        for (int q = 0; q < 4; ++q) {
            const int k = (c >> 2) + 64 * q;
            float4 o;
            o.x = o_lds[jj4 + 0][k];
            o.y = o_lds[jj4 + 1][k];
            o.z = o_lds[jj4 + 2][k];
            o.w = o_lds[jj4 + 3][k];
            *reinterpret_cast<float4*>(orow + k * 64 + p * OROWS + jj4) = o;
        }
        __syncthreads();
    }
}

extern "C" void kernel_launch(void* const* d_in, const int* in_sizes, int n_in,
                              void* d_out, int out_size, void* d_ws, size_t ws_size,
                              hipStream_t stream) {
    const float* u  = (const float*)d_in[0];
    const float* b1 = (const float*)d_in[1];
    const float* a1 = (const float*)d_in[2];
    const float* b2 = (const float*)d_in[3];
    const float* a2 = (const float*)d_in[4];
    float* out = (float*)d_out;

    const int B = in_sizes[0] / T_LEN;   // 512
    whsys_kernel<<<B, NTH, 0, stream>>>(u, b1, a1, b2, a2, out);
}

// Round 4
// 24.695 us; speedup vs baseline: 2.0472x; 1.1046x over previous
//
#include <hip/hip_runtime.h>
#include <hip/hip_fp16.h>

// Wiener-Hammerstein fused overlap-save, f16x4-packed LDS u, b128 staging.
//   y1 = IIR(b1,a1,n_k=1)(u);  v = whf(y1);  out = IIR(b2,a2,n_k=0)(v)
// Thread owns chunk k=c (64 samples). Warm-up from zero state starting 104
// early: stage-1 runs 104 (rho1^104 ~ 1e-13), stage-2 runs 72 before keep
// (rho2^72 ~ 4.7e-4; threshold 2.4e-2). u stored in LDS as f16x4 (one
// ds_read_b64 = 4 samples); outputs staged as float4 in a chunk-major
// XOR-swizzled buffer so both LDS sides are even-spread and global stores
// are 128B-contiguous.

constexpr int T_LEN = 16384;
constexpr int NTH   = 256;

__global__ __launch_bounds__(NTH, 2)
void whsys_kernel(const float* __restrict__ u,
                  const float* __restrict__ b1v, const float* __restrict__ a1v,
                  const float* __restrict__ b2v, const float* __restrict__ a2v,
                  float* __restrict__ out)
{
    // u4[m][k ^ m], m = (t&63)>>2, k = t>>6 : f16x4 = samples 4m..4m+3 of
    // chunk k. XOR swizzle -> phase-0 transposed writes and compute reads
    // both hit every bank-pair evenly (verified 4 accesses/pair = b64 floor).
    __shared__ uint2  u4[16 * 256];   // 32 KB
    // o_st[k][g ^ (k&7)] float4: pass-local 32 outputs per chunk. Writes
    // (fixed g, lanes k) and transposed reads both even across bank-quads.
    __shared__ float4 o_st[256 * 8];  // 32 KB  (total 64 KB -> 2 blk/CU)

    const int c = threadIdx.x;
    const float* __restrict__ urow = u   + (size_t)blockIdx.x * T_LEN;
    float*       __restrict__ orow = out + (size_t)blockIdx.x * T_LEN;

    const float b10=b1v[0], b11=b1v[1], b12=b1v[2];
    const float a10=a1v[0], a11=a1v[1], a12=a1v[2];
    const float b20=b2v[0], b21=b2v[1], b22=b2v[2];
    const float a20=a2v[0], a21=a2v[1], a22=a2v[2];

    // ---- phase 0: coalesced float4 load -> f16x4 pack -> swizzled LDS ------
    #pragma unroll
    for (int q = 0; q < 16; ++q) {
        const int t0 = q * 1024 + c * 4;
        const float4 v = *reinterpret_cast<const float4*>(urow + t0);
        const int k  = q * 16 + (c >> 4);
        const int m4 = c & 15;
        const __half2 h01 = __floats2half2_rn(v.x, v.y);
        const __half2 h23 = __floats2half2_rn(v.z, v.w);
        uint2 pk;
        pk.x = __builtin_bit_cast(unsigned int, h01);
        pk.y = __builtin_bit_cast(unsigned int, h23);
        u4[m4 * 256 + (k ^ m4)] = pk;
    }
    __syncthreads();

    // ---- recurrence state (register-renamed by full unroll) ----------------
    float u1=0.f,u2r=0.f,u3=0.f, y1=0.f,y2=0.f,y3=0.f;   // stage 1
    float v1=0.f,v2s=0.f, w1=0.f,w2=0.f,w3=0.f;          // stage 2

    auto step1 = [&](float ut) -> float {
        const float x = fmaf(b12,u3, fmaf(b11,u2r, b10*u1));  // n_k=1 FIR
        const float y = fmaf(-a10,y1, fmaf(-a11,y2, fmaf(-a12,y3, x)));
        u3=u2r; u2r=u1; u1=ut;
        y3=y2; y2=y1; y1=y;
        return y;
    };
    auto nl = [&](float y) -> float {                     // -elu(-10/11 y)
        const float e = 1.f - __expf(-0.9090909090909091f * y);
        return (y < 0.f) ? 0.9090909090909091f * y : e;
    };
    auto step2 = [&](float vt) -> float {
        const float x = fmaf(b22,v2s, fmaf(b21,v1, b20*vt));  // n_k=0 FIR
        const float w = fmaf(-a20,w1, fmaf(-a21,w2, fmaf(-a22,w3, x)));
        v2s=v1; v1=vt;
        w3=w2; w2=w1; w1=w;
        return w;
    };

    const int  kb0 = (c >= 2) ? c - 2 : 0;   // clamped columns; values zeroed
    const int  kb1 = (c >= 1) ? c - 1 : 0;
    const bool z0  = (c < 2), z1 = (c < 1);

    auto rd4 = [&](int kcol, bool zero, int m) -> float4 {   // m compile-time
        uint2 pk = u4[m * 256 + (kcol ^ m)];
        if (zero) { pk.x = 0u; pk.y = 0u; }
        const __half2 h01 = __builtin_bit_cast(__half2, pk.x);
        const __half2 h23 = __builtin_bit_cast(__half2, pk.y);
        return make_float4(__half2float(h01.x), __half2float(h01.y),
                           __half2float(h23.x), __half2float(h23.y));
    };

    // ---- A: stage-1 only, col c-2, r = 24..55 ------------------------------
    #pragma unroll
    for (int m = 6; m < 14; ++m) {
        const float4 uu = rd4(kb0, z0, m);
        step1(uu.x); step1(uu.y); step1(uu.z); step1(uu.w);
    }
    // ---- B: fused discard, col c-2, r = 56..63 (stage-2 starts here) -------
    #pragma unroll
    for (int m = 14; m < 16; ++m) {
        const float4 uu = rd4(kb0, z0, m);
        step2(nl(step1(uu.x))); step2(nl(step1(uu.y)));
        step2(nl(step1(uu.z))); step2(nl(step1(uu.w)));
    }
    // ---- C: fused discard, col c-1, r = 0..63 ------------------------------
    #pragma unroll
    for (int m = 0; m < 16; ++m) {
        const float4 uu = rd4(kb1, z1, m);
        step2(nl(step1(uu.x))); step2(nl(step1(uu.y)));
        step2(nl(step1(uu.z))); step2(nl(step1(uu.w)));
    }
    // ---- D: fused keep, col c, 2 passes x 32 outputs -----------------------
    #pragma unroll
    for (int p = 0; p < 2; ++p) {
        #pragma unroll
        for (int g = 0; g < 8; ++g) {
            const float4 uu = rd4(c, false, p * 8 + g);
            float4 ob;
            ob.x = step2(nl(step1(uu.x)));
            ob.y = step2(nl(step1(uu.y)));
            ob.z = step2(nl(step1(uu.z)));
            ob.w = step2(nl(step1(uu.w)));
            o_st[c * 8 + (g ^ (c & 7))] = ob;
        }
        __syncthreads();
        // store: lane covers t = 64k + 32p + 4e..+3; 8 lanes = 128B contiguous
        #pragma unroll
        for (int i = 0; i < 8; ++i) {
            const int k = i * 32 + (c >> 3);
            const int e = c & 7;
            const float4 ov = o_st[k * 8 + (e ^ (k & 7))];
            *reinterpret_cast<float4*>(orow + k * 64 + p * 32 + e * 4) = ov;
        }
        __syncthreads();
    }
}

extern "C" void kernel_launch(void* const* d_in, const int* in_sizes, int n_in,
                              void* d_out, int out_size, void* d_ws, size_t ws_size,
                              hipStream_t stream) {
    const float* u  = (const float*)d_in[0];
    const float* b1 = (const float*)d_in[1];
    const float* a1 = (const float*)d_in[2];
    const float* b2 = (const float*)d_in[3];
    const float* a2 = (const float*)d_in[4];
    float* out = (float*)d_out;

    const int B = in_sizes[0] / T_LEN;   // 512
    whsys_kernel<<<B, NTH, 0, stream>>>(u, b1, a1, b2, a2, out);
}

// Round 5
// 21.369 us; speedup vs baseline: 2.3658x; 1.1556x over previous
//
#include <hip/hip_runtime.h>
#include <hip/hip_fp16.h>

// Wiener-Hammerstein, EXACT chunk-state passing (no warm-up redundancy).
//   y1 = IIR(b1,a1,n_k=1)(u);  v = whf(y1);  out = IIR(b2,a2,n_k=0)(v)
// Each thread owns chunk c (64 samples of one row). Linearity =>
//   pass 1 : stage-1 zero-y-init local solution (exact u inputs), share
//            3-float final state D1[c] via LDS. Exact incoming state
//            E1[c] = D1[c-1] (M1^64 ~ 7e-9, next term negligible).
//   pass 2a: y1_exact = y1_local + homogeneous(E1); v = whf(y1_exact)
//            (med3 form). Share v tail (2 floats).
//   pass 2b: stage-2 zero-y-init local with exact v; share D2[c].
//   pass 3 : E2[c] = D2[c-1] + A2*D2[c-2], A2 = M2^64 (6 on-device 3x3
//            squarings; M2^128 ~ 1.4e-6 negligible); out = y2_local +
//            homogeneous(E2), staged through swizzled LDS for coalesced
//            float4 stores (R1: strided stores cost 4.6x write amplif.).
// u staged in LDS as f16x4 (R2: strided global reads cost 4x L2 amplif.).

constexpr int T_LEN = 16384;
constexpr int NTH   = 256;

__global__ __launch_bounds__(NTH, 2)
void whsys_kernel(const float* __restrict__ u,
                  const float* __restrict__ b1v, const float* __restrict__ a1v,
                  const float* __restrict__ b2v, const float* __restrict__ a2v,
                  float* __restrict__ out)
{
    __shared__ uint2  u4[16 * 256];     // 32 KB  f16x4: samples 4m..4m+3 of chunk k at [m][k^m]
    __shared__ float4 o_st[256 * 8];    // 32 KB  output staging (R4 layout)
    __shared__ float4 d1s[NTH + 1];     // stage-1 chunk-final states (+1 zero pad)
    __shared__ float4 d2s[NTH + 2];     // stage-2 chunk-final states (+2 zero pad)
    __shared__ float2 vts[NTH + 1];     // v tails (v[62], v[63]) (+1 zero pad)

    const int c = threadIdx.x;
    const float* __restrict__ urow = u   + (size_t)blockIdx.x * T_LEN;
    float*       __restrict__ orow = out + (size_t)blockIdx.x * T_LEN;

    const float b10=b1v[0], b11=b1v[1], b12=b1v[2];
    const float a10=a1v[0], a11=a1v[1], a12=a1v[2];
    const float b20=b2v[0], b21=b2v[1], b22=b2v[2];
    const float a20=a2v[0], a21=a2v[1], a22=a2v[2];

    // ---- phase 0: coalesced float4 load -> f16x4 pack -> swizzled LDS ------
    #pragma unroll
    for (int q = 0; q < 16; ++q) {
        const int t0 = q * 1024 + c * 4;
        const float4 v = *reinterpret_cast<const float4*>(urow + t0);
        const int k  = q * 16 + (c >> 4);
        const int m4 = c & 15;
        const __half2 h01 = __floats2half2_rn(v.x, v.y);
        const __half2 h23 = __floats2half2_rn(v.z, v.w);
        uint2 pk;
        pk.x = __builtin_bit_cast(unsigned int, h01);
        pk.y = __builtin_bit_cast(unsigned int, h23);
        u4[m4 * 256 + (k ^ m4)] = pk;
    }
    if (c == 0) { d1s[0] = make_float4(0,0,0,0); vts[0] = make_float2(0,0); }
    if (c < 2)  { d2s[c] = make_float4(0,0,0,0); }

    // ---- A2 = M2^64 (companion matrix of a2), 6 squarings (overlaps loads) -
    float A[9] = {-a20, -a21, -a22,  1.f, 0.f, 0.f,  0.f, 1.f, 0.f};
    #pragma unroll
    for (int it = 0; it < 6; ++it) {
        float Bm[9];
        #pragma unroll
        for (int i = 0; i < 3; ++i)
            #pragma unroll
            for (int j = 0; j < 3; ++j)
                Bm[i*3+j] = fmaf(A[i*3+0], A[0+j],
                             fmaf(A[i*3+1], A[3+j], A[i*3+2] * A[6+j]));
        #pragma unroll
        for (int i = 0; i < 9; ++i) A[i] = Bm[i];
    }
    __syncthreads();

    auto unpack = [](uint2 pk) -> float4 {
        const __half2 h01 = __builtin_bit_cast(__half2, pk.x);
        const __half2 h23 = __builtin_bit_cast(__half2, pk.y);
        return make_float4(__half2float(h01.x), __half2float(h01.y),
                           __half2float(h23.x), __half2float(h23.y));
    };

    // ---- pass 1: stage-1 local (zero y-init, exact u) -----------------------
    float y1v[64];
    {
        // u history u[-1],u[-2],u[-3] = samples 63,62,61 of chunk c-1 (m=15)
        const int kc = (c > 0) ? c - 1 : 0;
        const float4 ut = unpack(u4[15 * 256 + (kc ^ 15)]);
        float u_m1 = (c > 0) ? ut.w : 0.f;
        float u_m2 = (c > 0) ? ut.z : 0.f;
        float u_m3 = (c > 0) ? ut.y : 0.f;
        #pragma unroll
        for (int g = 0; g < 16; ++g) {
            const float4 uu = unpack(u4[g * 256 + (c ^ g)]);
            const float us[4] = {uu.x, uu.y, uu.z, uu.w};
            #pragma unroll
            for (int e = 0; e < 4; ++e) {
                const int j = g * 4 + e;
                const float x = fmaf(b12, u_m3, fmaf(b11, u_m2, b10 * u_m1));
                const float ym1 = (j >= 1) ? y1v[j-1] : 0.f;
                const float ym2 = (j >= 2) ? y1v[j-2] : 0.f;
                const float ym3 = (j >= 3) ? y1v[j-3] : 0.f;
                y1v[j] = fmaf(-a10, ym1, fmaf(-a11, ym2, fmaf(-a12, ym3, x)));
                u_m3 = u_m2; u_m2 = u_m1; u_m1 = us[e];
            }
        }
    }
    d1s[c + 1] = make_float4(y1v[63], y1v[62], y1v[61], 0.f);
    __syncthreads();

    // ---- pass 2a: y1 correction + whf (in place) ----------------------------
    {
        const float4 E1 = d1s[c];                 // exact (y[-1],y[-2],y[-3])
        float h1 = E1.x, h2 = E1.y, h3 = E1.z;
        #pragma unroll
        for (int j = 0; j < 64; ++j) {
            const float h = fmaf(-a10, h1, fmaf(-a11, h2, -a12 * h3));
            h3 = h2; h2 = h1; h1 = h;
            const float y1 = y1v[j] + h;
            // whf(y) = median(k*y, 1 - exp(-k*y), 0),  k = 10/11
            const float t1 = 0.9090909090909091f * y1;
            const float bb = 1.f - __expf(-t1);
            y1v[j] = __builtin_amdgcn_fmed3f(t1, bb, 0.f);   // v[j]
        }
    }
    vts[c + 1] = make_float2(y1v[62], y1v[63]);   // (v[-2], v[-1]) for chunk c+1
    __syncthreads();

    // ---- pass 2b: stage-2 local (zero y-init, exact v) ----------------------
    float y2a[64];
    {
        const float2 vt = vts[c];
        float v_m1 = vt.y, v_m2 = vt.x;
        #pragma unroll
        for (int j = 0; j < 64; ++j) {
            const float vj = y1v[j];
            const float x = fmaf(b22, v_m2, fmaf(b21, v_m1, b20 * vj));
            const float ym1 = (j >= 1) ? y2a[j-1] : 0.f;
            const float ym2 = (j >= 2) ? y2a[j-2] : 0.f;
            const float ym3 = (j >= 3) ? y2a[j-3] : 0.f;
            y2a[j] = fmaf(-a20, ym1, fmaf(-a21, ym2, fmaf(-a22, ym3, x)));
            v_m2 = v_m1; v_m1 = vj;
        }
    }
    d2s[c + 2] = make_float4(y2a[63], y2a[62], y2a[61], 0.f);
    __syncthreads();

    // ---- pass 3: E2 = D2[c-1] + A2*D2[c-2]; correct + staged stores ---------
    {
        const float4 Dm1 = d2s[c + 1];
        const float4 Dm2 = d2s[c];
        float g1 = fmaf(A[0], Dm2.x, fmaf(A[1], Dm2.y, fmaf(A[2], Dm2.z, Dm1.x)));
        float g2 = fmaf(A[3], Dm2.x, fmaf(A[4], Dm2.y, fmaf(A[5], Dm2.z, Dm1.y)));
        float g3 = fmaf(A[6], Dm2.x, fmaf(A[7], Dm2.y, fmaf(A[8], Dm2.z, Dm1.z)));
        #pragma unroll
        for (int p = 0; p < 2; ++p) {
            #pragma unroll
            for (int g8 = 0; g8 < 8; ++g8) {
                float ob[4];
                #pragma unroll
                for (int e = 0; e < 4; ++e) {
                    const int j = p * 32 + g8 * 4 + e;
                    const float h = fmaf(-a20, g1, fmaf(-a21, g2, -a22 * g3));
                    g3 = g2; g2 = g1; g1 = h;
                    ob[e] = y2a[j] + h;
                }
                o_st[c * 8 + (g8 ^ (c & 7))] =
                    make_float4(ob[0], ob[1], ob[2], ob[3]);
            }
            __syncthreads();
            // store: lane covers t = 64k + 32p + 4e..+3; 8 lanes = 128B contig
            #pragma unroll
            for (int i = 0; i < 8; ++i) {
                const int k = i * 32 + (c >> 3);
                const int e = c & 7;
                const float4 ov = o_st[k * 8 + (e ^ (k & 7))];
                *reinterpret_cast<float4*>(orow + k * 64 + p * 32 + e * 4) = ov;
            }
            __syncthreads();
        }
    }
}

extern "C" void kernel_launch(void* const* d_in, const int* in_sizes, int n_in,
                              void* d_out, int out_size, void* d_ws, size_t ws_size,
                              hipStream_t stream) {
    const float* u  = (const float*)d_in[0];
    const float* b1 = (const float*)d_in[1];
    const float* a1 = (const float*)d_in[2];
    const float* b2 = (const float*)d_in[3];
    const float* a2 = (const float*)d_in[4];
    float* out = (float*)d_out;

    const int B = in_sizes[0] / T_LEN;   // 512
    whsys_kernel<<<B, NTH, 0, stream>>>(u, b1, a1, b2, a2, out);
}

// Round 6
// 21.336 us; speedup vs baseline: 2.3694x; 1.0015x over previous
//
#include <hip/hip_runtime.h>
#include <hip/hip_fp16.h>

// Wiener-Hammerstein, exact chunk-state passing, CHUNK=32 / 512 threads.
//   y1 = IIR(b1,a1,n_k=1)(u);  v = whf(y1);  out = IIR(b2,a2,n_k=0)(v)
// R5 post-mortem: 21.4us vs ~12us arithmetic floor = exposed latency at
// 2 waves/SIMD. This version doubles occupancy (4 waves/SIMD): CHUNK=32
// halves register arrays and chains; o_st staging aliases the dead u4
// LDS (u unread after pass 1) -> ~53 KB LDS; __launch_bounds__(512,4).
// Exact-state terms at CHUNK=32: E1 = D1[c-1] + A1*D1[c-2]  (A1 = C1^32,
// trunc rho1^64 ~ 7e-9); E2 = D2[c-1] + A2*D2[c-2] + A2q*D2[c-3]
// (A2 = C2^32, A2q = C2^64, trunc rho2^96 ~ 4e-5). v-tails use LOCAL y1
// tails (err rho1^30*|E1| ~ 1e-3 << 2.4e-2 budget).

constexpr int T_LEN = 16384;
constexpr int NTH   = 512;
constexpr int NCH   = 512;   // chunks per row (CHUNK = 32)

__global__ __launch_bounds__(NTH, 4)
void whsys_kernel(const float* __restrict__ u,
                  const float* __restrict__ b1v, const float* __restrict__ a1v,
                  const float* __restrict__ b2v, const float* __restrict__ a2v,
                  float* __restrict__ out)
{
    // u4[m][k64 ^ m] (uint2 = f16x4): samples 4m..4m+3 of 64-sample seg k64
    // (R5-verified conflict-free layout). o_st ALIASES u4 (dead after pass1):
    // float4 [256 chunks][8 quads], slot q ^ (chunk&7) -> b128 floor both ways.
    __shared__ __align__(16) unsigned char smem[32768];
    uint2*  u4   = reinterpret_cast<uint2*>(smem);
    float4* o_st = reinterpret_cast<float4*>(smem);
    __shared__ float4 d1s[NCH + 2];   // stage-1 local tails (+2 zero pad)
    __shared__ float4 d2s[NCH + 3];   // stage-2 local tails (+3 zero pad)
    __shared__ float2 vts[NCH + 1];   // v tails (v[-2], v[-1]) (+1 zero pad)

    const int c = threadIdx.x;
    const float* __restrict__ urow = u   + (size_t)blockIdx.x * T_LEN;
    float*       __restrict__ orow = out + (size_t)blockIdx.x * T_LEN;

    const float b10=b1v[0], b11=b1v[1], b12=b1v[2];
    const float a10=a1v[0], a11=a1v[1], a12=a1v[2];
    const float b20=b2v[0], b21=b2v[1], b22=b2v[2];
    const float a20=a2v[0], a21=a2v[1], a22=a2v[2];

    // ---- phase 0: coalesced float4 load -> f16x4 pack -> swizzled LDS ------
    #pragma unroll
    for (int q = 0; q < 8; ++q) {
        const int t0 = q * 2048 + c * 4;
        const float4 v = *reinterpret_cast<const float4*>(urow + t0);
        const int k64 = q * 32 + (c >> 4);
        const int m   = c & 15;
        const __half2 h01 = __floats2half2_rn(v.x, v.y);
        const __half2 h23 = __floats2half2_rn(v.z, v.w);
        uint2 pk;
        pk.x = __builtin_bit_cast(unsigned int, h01);
        pk.y = __builtin_bit_cast(unsigned int, h23);
        u4[m * 256 + (k64 ^ m)] = pk;
    }
    if (c < 2) d1s[c] = make_float4(0,0,0,0);
    if (c < 3) d2s[c] = make_float4(0,0,0,0);
    if (c == 0) vts[0] = make_float2(0,0);

    // ---- A1 = C1^32 (5 squarings), A2 = C2^32, A2q = C2^64 -----------------
    float A1[9] = {-a10,-a11,-a12, 1.f,0.f,0.f, 0.f,1.f,0.f};
    float A2[9] = {-a20,-a21,-a22, 1.f,0.f,0.f, 0.f,1.f,0.f};
    float A2q[9];
    #pragma unroll
    for (int it = 0; it < 5; ++it) {
        float B1[9], B2[9];
        #pragma unroll
        for (int i = 0; i < 3; ++i)
            #pragma unroll
            for (int j = 0; j < 3; ++j) {
                B1[i*3+j] = fmaf(A1[i*3], A1[j], fmaf(A1[i*3+1], A1[3+j], A1[i*3+2]*A1[6+j]));
                B2[i*3+j] = fmaf(A2[i*3], A2[j], fmaf(A2[i*3+1], A2[3+j], A2[i*3+2]*A2[6+j]));
            }
        #pragma unroll
        for (int i = 0; i < 9; ++i) { A1[i] = B1[i]; A2[i] = B2[i]; }
    }
    #pragma unroll
    for (int i = 0; i < 3; ++i)
        #pragma unroll
        for (int j = 0; j < 3; ++j)
            A2q[i*3+j] = fmaf(A2[i*3], A2[j], fmaf(A2[i*3+1], A2[3+j], A2[i*3+2]*A2[6+j]));
    __syncthreads();

    auto unpack = [](uint2 pk) -> float4 {
        const __half2 h01 = __builtin_bit_cast(__half2, pk.x);
        const __half2 h23 = __builtin_bit_cast(__half2, pk.y);
        return make_float4(__half2float(h01.x), __half2float(h01.y),
                           __half2float(h23.x), __half2float(h23.y));
    };
    auto whf = [](float y) -> float {   // -elu(-10/11 y) = med3(ky, 1-e^-ky, 0)
        const float t1 = 0.9090909090909091f * y;
        const float e  = 1.f - __expf(-t1);
        return __builtin_amdgcn_fmed3f(t1, e, 0.f);
    };

    float arr[32];                       // y1 local, overwritten by y2 local

    // ---- pass 1: stage-1 local (zero y-init, exact u), chunk c -------------
    {
        float u_m1 = 0.f, u_m2 = 0.f, u_m3 = 0.f;
        if (c > 0) {                     // u[32c-4 .. 32c-1] quad
            const int km1 = (c - 1) >> 1;
            const int mm1 = 8 * ((c - 1) & 1) + 7;
            const float4 ut = unpack(u4[mm1 * 256 + (km1 ^ mm1)]);
            u_m1 = ut.w; u_m2 = ut.z; u_m3 = ut.y;
        }
        float yr1 = 0.f, yr2 = 0.f, yr3 = 0.f;
        #pragma unroll
        for (int g = 0; g < 8; ++g) {
            const int m  = 8 * (c & 1) + g;
            const int kk = c >> 1;
            const float4 uu = unpack(u4[m * 256 + (kk ^ m)]);
            const float us[4] = {uu.x, uu.y, uu.z, uu.w};
            #pragma unroll
            for (int e = 0; e < 4; ++e) {
                const float x = fmaf(b12, u_m3, fmaf(b11, u_m2, b10 * u_m1));
                const float y = fmaf(-a10, yr1, fmaf(-a11, yr2, fmaf(-a12, yr3, x)));
                arr[g * 4 + e] = y;
                u_m3 = u_m2; u_m2 = u_m1; u_m1 = us[e];
                yr3 = yr2; yr2 = yr1; yr1 = y;
            }
        }
        d1s[c + 2] = make_float4(yr1, yr2, yr3, 0.f);        // y[31],[30],[29]
        vts[c + 1] = make_float2(whf(yr2), whf(yr1));        // (v[-2], v[-1])
    }
    __syncthreads();

    // ---- pass 2: y1 correction + whf + stage-2 local (fused) ---------------
    {
        const float4 P = d1s[c + 1], Q = d1s[c];             // E1 = P + A1*Q
        float h1 = fmaf(A1[0], Q.x, fmaf(A1[1], Q.y, fmaf(A1[2], Q.z, P.x)));
        float h2 = fmaf(A1[3], Q.x, fmaf(A1[4], Q.y, fmaf(A1[5], Q.z, P.y)));
        float h3 = fmaf(A1[6], Q.x, fmaf(A1[7], Q.y, fmaf(A1[8], Q.z, P.z)));
        const float2 vt = vts[c];
        float v1r = vt.y, v2r = vt.x;
        float z1 = 0.f, z2 = 0.f, z3 = 0.f;
        #pragma unroll
        for (int j = 0; j < 32; ++j) {
            const float hn = fmaf(-a10, h1, fmaf(-a11, h2, -a12 * h3));
            h3 = h2; h2 = h1; h1 = hn;
            const float v = whf(arr[j] + hn);
            const float x = fmaf(b22, v2r, fmaf(b21, v1r, b20 * v));
            const float z = fmaf(-a20, z1, fmaf(-a21, z2, fmaf(-a22, z3, x)));
            v2r = v1r; v1r = v;
            z3 = z2; z2 = z1; z1 = z;
            arr[j] = z;                                      // y2 local
        }
        d2s[c + 3] = make_float4(z1, z2, z3, 0.f);
    }
    __syncthreads();

    // ---- pass 3: E2 correction in place ------------------------------------
    {
        const float4 R = d2s[c + 2], S = d2s[c + 1], Tt = d2s[c];
        float g1 = fmaf(A2[0], S.x, fmaf(A2[1], S.y, fmaf(A2[2], S.z,
                   fmaf(A2q[0], Tt.x, fmaf(A2q[1], Tt.y, fmaf(A2q[2], Tt.z, R.x))))));
        float g2 = fmaf(A2[3], S.x, fmaf(A2[4], S.y, fmaf(A2[5], S.z,
                   fmaf(A2q[3], Tt.x, fmaf(A2q[4], Tt.y, fmaf(A2q[5], Tt.z, R.y))))));
        float g3 = fmaf(A2[6], S.x, fmaf(A2[7], S.y, fmaf(A2[8], S.z,
                   fmaf(A2q[6], Tt.x, fmaf(A2q[7], Tt.y, fmaf(A2q[8], Tt.z, R.z))))));
        #pragma unroll
        for (int j = 0; j < 32; ++j) {
            const float gn = fmaf(-a20, g1, fmaf(-a21, g2, -a22 * g3));
            g3 = g2; g2 = g1; g1 = gn;
            arr[j] += gn;
        }
    }

    // ---- store: 2 passes of 256 chunks via swizzled o_st (aliases u4) ------
    #pragma unroll
    for (int p = 0; p < 2; ++p) {
        if ((c >> 8) == p) {
            #pragma unroll
            for (int q = 0; q < 8; ++q)
                o_st[(c & 255) * 8 + (q ^ (c & 7))] =
                    make_float4(arr[4*q], arr[4*q+1], arr[4*q+2], arr[4*q+3]);
        }
        __syncthreads();
        #pragma unroll
        for (int s = 0; s < 4; ++s) {
            const int f = s * 512 + c;          // 2048 float4 per pass
            const int k = f >> 3, q = f & 7;
            const float4 ov = o_st[k * 8 + (q ^ (k & 7))];
            *reinterpret_cast<float4*>(orow + (p * 256 + k) * 32 + q * 4) = ov;
        }
        if (p == 0) __syncthreads();
    }
}

extern "C" void kernel_launch(void* const* d_in, const int* in_sizes, int n_in,
                              void* d_out, int out_size, void* d_ws, size_t ws_size,
                              hipStream_t stream) {
    const float* u  = (const float*)d_in[0];
    const float* b1 = (const float*)d_in[1];
    const float* a1 = (const float*)d_in[2];
    const float* b2 = (const float*)d_in[3];
    const float* a2 = (const float*)d_in[4];
    float* out = (float*)d_out;

    const int B = in_sizes[0] / T_LEN;   // 512
    whsys_kernel<<<B, NTH, 0, stream>>>(u, b1, a1, b2, a2, out);
}